// Round 5
// baseline (528.913 us; speedup 1.0000x reference)
//
#include <hip/hip_runtime.h>

// RGCNConv: out_i = x_i @ W_root + bias + sum_r mean_{j in N_r(i)} x_j @ W_r
//
// AGGREGATE-FIRST + bf16 MFMA finalize, L3-AWARE CHUNKING:
//   sort edges by seg = dst*R + type once; then per feature-chunk (CW<=64 so the
//   full working set {x, mean, out, spack} stays under the 256 MB Infinity Cache):
//     aggregate: mean_bf[seg][cc] = bf16(mean of x[src][c0+cc])
//     MFMA GEMM: out[N,128] (+)= [x_bf | mean_bf] @ WallT_bf (+bias on pass 0)

constexpr int D = 128;
constexpr int R = 8;

typedef __bf16 bf16x8 __attribute__((ext_vector_type(8)));
typedef float  f32x4  __attribute__((ext_vector_type(4)));
typedef unsigned short u16x8 __attribute__((ext_vector_type(8)));
typedef unsigned short u16x4 __attribute__((ext_vector_type(4)));

__device__ __forceinline__ unsigned short f2bf(float f) {
    unsigned u = __builtin_bit_cast(unsigned, f);
    u += 0x7FFFu + ((u >> 16) & 1u);          // round-to-nearest-even
    return (unsigned short)(u >> 16);
}

// ---- sort phase ----
__global__ __launch_bounds__(256)
void hist_kernel(const int* __restrict__ dst, const int* __restrict__ et,
                 int* __restrict__ hist, int E) {
    int e = blockIdx.x * 256 + threadIdx.x;
    if (e < E) atomicAdd(&hist[dst[e] * R + et[e]], 1);
}

__global__ __launch_bounds__(256)
void block_sums_kernel(const int* __restrict__ hs, int* __restrict__ bsum, int n) {
    __shared__ int sh[256];
    int i = blockIdx.x * 256 + threadIdx.x;
    sh[threadIdx.x] = (i < n) ? hs[i] : 0;
    __syncthreads();
    for (int off = 128; off > 0; off >>= 1) {
        if (threadIdx.x < off) sh[threadIdx.x] += sh[threadIdx.x + off];
        __syncthreads();
    }
    if (threadIdx.x == 0) bsum[blockIdx.x] = sh[0];
}

__global__ __launch_bounds__(64)
void scan_bsum_kernel(int* __restrict__ bsum, int nb) {
    int lane = threadIdx.x;
    int carry = 0;
    for (int base = 0; base < nb; base += 64) {
        int i = base + lane;
        int orig = (i < nb) ? bsum[i] : 0;
        int v = orig;
        #pragma unroll
        for (int off = 1; off < 64; off <<= 1) {
            int u = __shfl_up(v, off, 64);
            if (lane >= off) v += u;
        }
        int tot = __shfl(v, 63, 64);
        if (i < nb) bsum[i] = carry + (v - orig);
        carry += tot;
    }
}

__global__ __launch_bounds__(256)
void scan_block_kernel(int* __restrict__ hs, const int* __restrict__ bsum,
                       int* __restrict__ cursor, int n, int E) {
    __shared__ int sh[256];
    int tid = threadIdx.x;
    int i = blockIdx.x * 256 + tid;
    int v = (i < n) ? hs[i] : 0;
    sh[tid] = v;
    __syncthreads();
    for (int off = 1; off < 256; off <<= 1) {
        int u = (tid >= off) ? sh[tid - off] : 0;
        __syncthreads();
        sh[tid] += u;
        __syncthreads();
    }
    int st = bsum[blockIdx.x] + sh[tid] - v;
    if (i < n) { hs[i] = st; cursor[i] = st; }
    if (i == n) hs[n] = E;
}

__global__ __launch_bounds__(256)
void reorder_kernel(const int* __restrict__ src, const int* __restrict__ dst,
                    const int* __restrict__ et, int* __restrict__ cursor,
                    int* __restrict__ spack, int E) {
    int e = blockIdx.x * 256 + threadIdx.x;
    if (e < E) {
        int pos = atomicAdd(&cursor[dst[e] * R + et[e]], 1);
        spack[pos] = src[e];
    }
}

// ---- aggregate: mean_bf[seg][CW] for feature cols [c0, c0+CW) ----
__global__ __launch_bounds__(256)
void aggregate_kernel(const float* __restrict__ x, const int* __restrict__ spack,
                      const int* __restrict__ hstart, unsigned short* __restrict__ mean,
                      int nseg, int tshift, int c0) {
    int idx = blockIdx.x * 256 + threadIdx.x;
    int seg = idx >> tshift;                      // CW/4 threads per seg
    int c4  = idx & ((1 << tshift) - 1);
    if (seg >= nseg) return;
    int p0 = hstart[seg], p1 = hstart[seg + 1];
    float a0 = 0.f, a1 = 0.f, a2 = 0.f, a3 = 0.f;
    for (int p = p0; p < p1; ++p) {
        int s = spack[p];
        float4 v = *(const float4*)(x + ((size_t)s << 7) + c0 + (c4 << 2));
        a0 += v.x; a1 += v.y; a2 += v.z; a3 += v.w;
    }
    float sc = (p1 > p0) ? (1.0f / (float)(p1 - p0)) : 0.0f;
    u16x4 o;
    o[0] = f2bf(a0 * sc); o[1] = f2bf(a1 * sc);
    o[2] = f2bf(a2 * sc); o[3] = f2bf(a3 * sc);
    *(u16x4*)(mean + ((size_t)seg << (tshift + 2)) + (c4 << 2)) = o;
}

// ---- build transposed bf16 weight block for one pass ----
__global__ __launch_bounds__(256)
void wallt_kernel(const float* __restrict__ Wroot, const float* __restrict__ W,
                  unsigned short* __restrict__ WallTc, int KW, int CW, int c0, int first) {
    int idx = blockIdx.x * 256 + threadIdx.x;
    if (idx >= 128 * KW) return;
    int n = idx / KW, kk = idx % KW;
    float v;
    if (first && kk < 128) {
        v = Wroot[kk * 128 + n];
    } else {
        int lk = kk - (first ? 128 : 0);
        int r = lk / CW, cc = lk % CW;
        v = W[((size_t)r * 128 + c0 + cc) * 128 + n];
    }
    WallTc[idx] = f2bf(v);
}

// ---- MFMA GEMM: out[128-tile][128] (+)= A_virtual @ WallTc ----
template<bool FIRST>
__global__ __launch_bounds__(256)
void mfma_gemm_kernel(const float* __restrict__ x,
                      const unsigned short* __restrict__ mean,
                      const unsigned short* __restrict__ WallTc,
                      const float* __restrict__ bias,
                      float* __restrict__ out,
                      int N, int NT, int KW, int MROW) {
    __shared__ unsigned short As[128][32];
    __shared__ unsigned short Bs[128][32];
    const int tid  = threadIdx.x;
    const int row0 = blockIdx.x * 128;
    const int lane = tid & 63;
    const int wid  = tid >> 6;
    const int wm   = wid >> 1;         // wave grid 2x2, each wave 64x64
    const int wn   = wid & 1;
    const int srow = tid >> 1;         // staging row 0..127
    const int sh16 = (tid & 1) * 16;   // staging k-offset (elems)

    f32x4 acc[4][4] = {};

    const int  node = row0 + srow;
    const bool nok  = node < N;

    for (int kt = 0; kt < NT; ++kt) {
        if (kt) __syncthreads();
        u16x8 a0, a1;
        #pragma unroll
        for (int j = 0; j < 8; ++j) { a0[j] = 0; a1[j] = 0; }
        if (FIRST && kt < 4) {
            if (nok) {
                const float4* xp = (const float4*)(x + (size_t)node * 128 + kt * 32 + sh16);
                float4 v0 = xp[0], v1 = xp[1], v2 = xp[2], v3 = xp[3];
                a0[0] = f2bf(v0.x); a0[1] = f2bf(v0.y); a0[2] = f2bf(v0.z); a0[3] = f2bf(v0.w);
                a0[4] = f2bf(v1.x); a0[5] = f2bf(v1.y); a0[6] = f2bf(v1.z); a0[7] = f2bf(v1.w);
                a1[0] = f2bf(v2.x); a1[1] = f2bf(v2.y); a1[2] = f2bf(v2.z); a1[3] = f2bf(v2.w);
                a1[4] = f2bf(v3.x); a1[5] = f2bf(v3.y); a1[6] = f2bf(v3.z); a1[7] = f2bf(v3.w);
            }
        } else {
            if (nok) {
                const u16x8* mp = (const u16x8*)(mean + (size_t)node * MROW
                                                 + (kt - (FIRST ? 4 : 0)) * 32 + sh16);
                a0 = mp[0]; a1 = mp[1];
            }
        }
        const u16x8* wp = (const u16x8*)(WallTc + (size_t)srow * KW + kt * 32 + sh16);
        u16x8 b0 = wp[0], b1 = wp[1];

        *(u16x8*)&As[srow][sh16]     = a0;
        *(u16x8*)&As[srow][sh16 + 8] = a1;
        *(u16x8*)&Bs[srow][sh16]     = b0;
        *(u16x8*)&Bs[srow][sh16 + 8] = b1;
        __syncthreads();

        const int kg = (lane >> 4) * 8;
        const int rl = lane & 15;
        bf16x8 av[4], bv[4];
        #pragma unroll
        for (int f = 0; f < 4; ++f) {
            av[f] = __builtin_bit_cast(bf16x8, *(const u16x8*)&As[wm * 64 + f * 16 + rl][kg]);
            bv[f] = __builtin_bit_cast(bf16x8, *(const u16x8*)&Bs[wn * 64 + f * 16 + rl][kg]);
        }
        #pragma unroll
        for (int mf = 0; mf < 4; ++mf)
            #pragma unroll
            for (int nf = 0; nf < 4; ++nf)
                acc[mf][nf] = __builtin_amdgcn_mfma_f32_16x16x32_bf16(av[mf], bv[nf],
                                                                     acc[mf][nf], 0, 0, 0);
    }

    const int rl = lane & 15;
    const int rg = lane >> 4;
    #pragma unroll
    for (int nf = 0; nf < 4; ++nf) {
        int n = wn * 64 + nf * 16 + rl;
        float bb = FIRST ? bias[n] : 0.0f;
        #pragma unroll
        for (int mf = 0; mf < 4; ++mf) {
            #pragma unroll
            for (int i = 0; i < 4; ++i) {
                int nd = row0 + wm * 64 + mf * 16 + rg * 4 + i;
                if (nd < N) {
                    size_t o = (size_t)nd * 128 + n;
                    if (FIRST) out[o] = acc[mf][nf][i] + bb;
                    else       out[o] += acc[mf][nf][i];
                }
            }
        }
    }
}

extern "C" void kernel_launch(void* const* d_in, const int* in_sizes, int n_in,
                              void* d_out, int out_size, void* d_ws, size_t ws_size,
                              hipStream_t stream) {
    const float* x     = (const float*)d_in[0];
    const float* W     = (const float*)d_in[1];
    const float* Wroot = (const float*)d_in[2];
    const float* bias  = (const float*)d_in[3];
    const int*   ei    = (const int*)d_in[4];
    const int*   et    = (const int*)d_in[5];
    float*       out   = (float*)d_out;

    const int N = in_sizes[0] / D;
    const int E = in_sizes[5];
    const int* src = ei;
    const int* dst = ei + E;

    const int NSEG = N * R;
    const int NB   = (NSEG + 256) / 256;

    const size_t fixed_bytes = ((size_t)(NSEG + 1) + NSEG + E + NB) * 4;
    const size_t walltc_max  = (size_t)128 * 1152 * 2;

    // CW capped at 64: working set {x 51 + mean 102 + out 51 + spack 6.4} MB < 256 MB L3.
    // CW=128 (R4) thrashed L3: FETCH 392 MB/dispatch from x re-fetches.
    int CW = 0, tshift = 0;
    const int cands[3]   = {64, 32, 16};
    const int tshifts[3] = {4, 3, 2};
    for (int i = 0; i < 3; ++i) {
        size_t need = (size_t)NSEG * cands[i] * 2 + walltc_max + fixed_bytes + 256;
        if (need <= ws_size) { CW = cands[i]; tshift = tshifts[i]; break; }
    }
    if (CW == 0) return;

    char* p = (char*)d_ws;
    unsigned short* mean   = (unsigned short*)p;  p += (size_t)NSEG * CW * 2;
    unsigned short* WallTc = (unsigned short*)p;  p += walltc_max;
    int* hstart = (int*)p;  p += (size_t)(NSEG + 1) * 4;
    int* cursor = (int*)p;  p += (size_t)NSEG * 4;
    int* spack  = (int*)p;  p += (size_t)E * 4;
    int* bsum   = (int*)p;

    // ---- sort by seg (once) ----
    hipMemsetAsync(hstart, 0, (size_t)(NSEG + 1) * 4, stream);
    hist_kernel<<<(E + 255) / 256, 256, 0, stream>>>(dst, et, hstart, E);
    block_sums_kernel<<<NB, 256, 0, stream>>>(hstart, bsum, NSEG);
    scan_bsum_kernel<<<1, 64, 0, stream>>>(bsum, NB);
    scan_block_kernel<<<NB, 256, 0, stream>>>(hstart, bsum, cursor, NSEG, E);
    reorder_kernel<<<(E + 255) / 256, 256, 0, stream>>>(src, dst, et, cursor, spack, E);

    // ---- per feature-chunk: aggregate + MFMA GEMM ----
    const int gx  = (N + 127) / 128;
    const int nch = D / CW;
    for (int c = 0; c < nch; ++c) {
        int c0    = c * CW;
        int first = (c == 0);
        long long aggth = (long long)NSEG << tshift;
        aggregate_kernel<<<(int)((aggth + 255) / 256), 256, 0, stream>>>(
            x, spack, hstart, mean, NSEG, tshift, c0);
        int KW   = (first ? 128 : 0) + R * CW;
        int NT   = KW / 32;
        int MROW = R * CW;
        wallt_kernel<<<(128 * KW + 255) / 256, 256, 0, stream>>>(
            Wroot, W, WallTc, KW, CW, c0, first);
        if (first)
            mfma_gemm_kernel<true><<<gx, 256, 0, stream>>>(
                x, mean, WallTc, bias, out, N, NT, KW, MROW);
        else
            mfma_gemm_kernel<false><<<gx, 256, 0, stream>>>(
                x, mean, WallTc, bias, out, N, NT, KW, MROW);
    }
}